// Round 1
// baseline (1691.452 us; speedup 1.0000x reference)
//
#include <hip/hip_runtime.h>
#include <hip/hip_bf16.h>

// Problem constants
#define B_ 2
#define T_ 1024
#define H_ 32
#define N_ 64
#define HN_ 2048
#define KVH_ 8
#define KVD_ 512
#define MTOK 2048        // B*T
#define SMN 7168         // concat small-gemm output width
#define KCAT 320

typedef __bf16 bf16x8 __attribute__((ext_vector_type(8)));
typedef float f32x4 __attribute__((ext_vector_type(4)));
typedef float f32x2 __attribute__((ext_vector_type(2)));

__device__ __forceinline__ float sigmf(float x) { return 1.f / (1.f + expf(-x)); }

// ---------------- prep kernels ----------------
__global__ void f2b_kernel(const float* __restrict__ in, __hip_bfloat16* __restrict__ out, int n) {
    int i = blockIdx.x * 256 + threadIdx.x;
    if (i < n) out[i] = __float2bfloat16(in[i]);
}

// in: rows x cols (f32). out: cols x rows (bf16), out[c*rows + r] = in[r*cols + c]
__global__ void transpose_f2b_kernel(const float* __restrict__ in, __hip_bfloat16* __restrict__ out,
                                     int rows, int cols) {
    long i = (long)blockIdx.x * 256 + threadIdx.x;
    if (i >= (long)rows * cols) return;
    int c = (int)(i / rows), r = (int)(i % rows);
    out[i] = __float2bfloat16(in[(size_t)r * cols + c]);
}

// Wcat: (7168 x 320) bf16, row j = weights producing concat output j, zero-padded K
__global__ void build_wcat_kernel(const float* __restrict__ w2, const float* __restrict__ a2,
                                  const float* __restrict__ v2, const float* __restrict__ g2,
                                  const float* __restrict__ k2, __hip_bfloat16* __restrict__ out) {
    long i = (long)blockIdx.x * 256 + threadIdx.x;
    if (i >= (long)SMN * KCAT) return;
    int j = (int)(i / KCAT), k = (int)(i % KCAT);
    float v = 0.f;
    if (j < 2048)      { if (k < 64)             v = w2[(size_t)k * 2048 + j]; }
    else if (j < 4096) { if (k >= 64 && k < 128)  v = a2[(size_t)(k - 64) * 2048 + (j - 2048)]; }
    else if (j < 4608) { if (k >= 128 && k < 160) v = v2[(size_t)(k - 128) * 512 + (j - 4096)]; }
    else if (j < 6656) { if (k >= 160 && k < 288) v = g2[(size_t)(k - 160) * 2048 + (j - 4608)]; }
    else               { if (k >= 288)            v = k2[(size_t)(k - 288) * 512 + (j - 6656)]; }
    out[i] = __float2bfloat16(v);
}

// ---------------- RMSNorm over HN per token -> bf16 ----------------
__global__ __launch_bounds__(256) void rmsnorm_kernel(const float* __restrict__ x,
                                                      const float* __restrict__ ln1,
                                                      __hip_bfloat16* __restrict__ out) {
    const int bt = blockIdx.x, tid = threadIdx.x;
    const float* row = x + (size_t)bt * HN_;
    float4 v0 = *(const float4*)(row + tid * 8);
    float4 v1 = *(const float4*)(row + tid * 8 + 4);
    float s = v0.x*v0.x + v0.y*v0.y + v0.z*v0.z + v0.w*v0.w
            + v1.x*v1.x + v1.y*v1.y + v1.z*v1.z + v1.w*v1.w;
    for (int m = 1; m < 64; m <<= 1) s += __shfl_xor(s, m);
    __shared__ float red[4];
    if ((tid & 63) == 0) red[tid >> 6] = s;
    __syncthreads();
    s = red[0] + red[1] + red[2] + red[3];
    float scale = rsqrtf(s * (1.f / HN_) + 1e-6f);
    float vals[8] = {v0.x, v0.y, v0.z, v0.w, v1.x, v1.y, v1.z, v1.w};
    #pragma unroll
    for (int j = 0; j < 8; ++j)
        out[(size_t)bt * HN_ + tid * 8 + j] = __float2bfloat16(vals[j] * scale * ln1[tid * 8 + j]);
}

// ---------------- apply tanh/sigmoid to xw/xg segments -> bf16 ----------------
__global__ void xwmod_kernel(const float* __restrict__ in, __hip_bfloat16* __restrict__ out) {
    long i = (long)blockIdx.x * 256 + threadIdx.x;
    if (i >= (long)MTOK * KCAT) return;
    int c = (int)(i % KCAT);
    float x = in[i];
    if (c < 64) x = tanhf(x);
    else if (c >= 160 && c < 288) x = sigmf(x);
    out[i] = __float2bfloat16(x);
}

// ---------------- generic MFMA GEMM: C[M,N] = A[M,K] * B[N,K]^T (+bias +addend) ----------------
__global__ __launch_bounds__(256) void gemm_bt(const __hip_bfloat16* __restrict__ A,
                                               const __hip_bfloat16* __restrict__ B,
                                               float* __restrict__ C, int M, int N, int K,
                                               const float* __restrict__ bias,
                                               const float* __restrict__ addend) {
    __shared__ __align__(16) __hip_bfloat16 As[64][40];
    __shared__ __align__(16) __hip_bfloat16 Bs[64][40];
    const int tid = threadIdx.x;
    const int wave = tid >> 6, lane = tid & 63;
    const int wr = (wave >> 1) * 32, wc = (wave & 1) * 32;
    const int brow = blockIdx.y << 6, bcol = blockIdx.x << 6;
    const int lrow = tid >> 2, lcol = (tid & 3) << 3;
    const int fr = lane & 15, ko = (lane >> 4) << 3;
    f32x4 acc[2][2] = {};
    for (int k0 = 0; k0 < K; k0 += 32) {
        uint4 av = *(const uint4*)(A + (size_t)(brow + lrow) * K + k0 + lcol);
        uint4 bv = *(const uint4*)(B + (size_t)(bcol + lrow) * K + k0 + lcol);
        *(uint4*)(&As[lrow][lcol]) = av;
        *(uint4*)(&Bs[lrow][lcol]) = bv;
        __syncthreads();
        bf16x8 af0 = *(const bf16x8*)(&As[wr + fr][ko]);
        bf16x8 af1 = *(const bf16x8*)(&As[wr + 16 + fr][ko]);
        bf16x8 bf0 = *(const bf16x8*)(&Bs[wc + fr][ko]);
        bf16x8 bf1 = *(const bf16x8*)(&Bs[wc + 16 + fr][ko]);
        acc[0][0] = __builtin_amdgcn_mfma_f32_16x16x32_bf16(af0, bf0, acc[0][0], 0, 0, 0);
        acc[0][1] = __builtin_amdgcn_mfma_f32_16x16x32_bf16(af0, bf1, acc[0][1], 0, 0, 0);
        acc[1][0] = __builtin_amdgcn_mfma_f32_16x16x32_bf16(af1, bf0, acc[1][0], 0, 0, 0);
        acc[1][1] = __builtin_amdgcn_mfma_f32_16x16x32_bf16(af1, bf1, acc[1][1], 0, 0, 0);
        __syncthreads();
    }
    const int cr = (lane >> 4) << 2, cc = lane & 15;
    #pragma unroll
    for (int i = 0; i < 2; ++i)
        #pragma unroll
        for (int j = 0; j < 2; ++j)
            #pragma unroll
            for (int r = 0; r < 4; ++r) {
                int row = brow + wr + i * 16 + cr + r;
                int col = bcol + wc + j * 16 + cc;
                float v = acc[i][j][r];
                if (bias) v += bias[col];
                if (addend) v += addend[(size_t)row * N + col];
                C[(size_t)row * N + col] = v;
            }
}

// ---------------- compose: per-token head math -> packed scan records ----------------
// record per (bh,t): 896B = bf16[5][64] {r, ksc, aa, bb, v} + f32[64] dec
__global__ __launch_bounds__(256) void compose_kernel(
    const float* __restrict__ RKV, const float* __restrict__ SM,
    const float* __restrict__ v_first, const float* __restrict__ k_first,
    const float* __restrict__ cosd, const float* __restrict__ sind,
    const float* __restrict__ R_bias, const float* __restrict__ K_bias,
    const float* __restrict__ V_bias, const float* __restrict__ w0,
    const float* __restrict__ a0, const float* __restrict__ v0b,
    const float* __restrict__ k0b, const float* __restrict__ ln_r,
    const float* __restrict__ ln_k, const float* __restrict__ r_k,
    char* __restrict__ SC, float* __restrict__ VB, float* __restrict__ SB) {
    __shared__ __align__(16) float rbuf[HN_];
    __shared__ __align__(16) float kbuf[KVD_];
    __shared__ __align__(16) float vbuf[KVD_];
    __shared__ float knorms[KVH_];
    __shared__ float cosb[64], sinb[64];
    const int bt = blockIdx.x;
    const int b = bt >> 10, t = bt & 1023;
    const int tid = threadIdx.x;
    const float* rkvrow = RKV + (size_t)bt * 3072;
    const float* smrow = SM + (size_t)bt * SMN;

    if (tid < 64) {
        cosb[tid] = cosd[(size_t)bt * 64 + tid];
        sinb[tid] = sind[(size_t)bt * 64 + tid];
    }

    const int h = tid >> 3;
    const int off = (tid & 7) << 3;
    const int n0 = tid << 3;
    float rraw[8];
    {
        float4 x0 = *(const float4*)(rkvrow + n0);
        float4 x1 = *(const float4*)(rkvrow + n0 + 4);
        float4 b0 = *(const float4*)(R_bias + n0);
        float4 b1 = *(const float4*)(R_bias + n0 + 4);
        rraw[0] = x0.x + b0.x; rraw[1] = x0.y + b0.y; rraw[2] = x0.z + b0.z; rraw[3] = x0.w + b0.w;
        rraw[4] = x1.x + b1.x; rraw[5] = x1.y + b1.y; rraw[6] = x1.z + b1.z; rraw[7] = x1.w + b1.w;
    }
    float rss = 0.f;
    #pragma unroll
    for (int j = 0; j < 8; ++j) { rss += rraw[j] * rraw[j]; rbuf[n0 + j] = rraw[j]; }
    rss += __shfl_xor(rss, 1); rss += __shfl_xor(rss, 2); rss += __shfl_xor(rss, 4);
    float rscale = rsqrtf(rss * (1.f / 64.f) + 1e-6f);

    const int kvh = tid >> 5;
    const int ko2 = (tid & 31) << 1;
    const int kidx = kvh * 64 + ko2;
    float kraw0 = rkvrow[2048 + kidx] + K_bias[kidx];
    float kraw1 = rkvrow[2048 + kidx + 1] + K_bias[kidx + 1];
    float kss = kraw0 * kraw0 + kraw1 * kraw1;
    kss += __shfl_xor(kss, 1); kss += __shfl_xor(kss, 2); kss += __shfl_xor(kss, 4);
    kss += __shfl_xor(kss, 8); kss += __shfl_xor(kss, 16);
    float kscale = rsqrtf(kss * (1.f / 64.f) + 1e-6f);
    kbuf[kidx] = kraw0; kbuf[kidx + 1] = kraw1;

    {   // v: bias + first-mix (pure elementwise)
        float va = rkvrow[2560 + kidx] + V_bias[kidx];
        float vb2 = rkvrow[2560 + kidx + 1] + V_bias[kidx + 1];
        float gv0 = sigmf(smrow[4096 + kidx] + v0b[kidx]);
        float gv1 = sigmf(smrow[4096 + kidx + 1] + v0b[kidx + 1]);
        vbuf[kidx] = va + (v_first[(size_t)bt * 512 + kidx] - va) * gv0;
        vbuf[kidx + 1] = vb2 + (v_first[(size_t)bt * 512 + kidx + 1] - vb2) * gv1;
    }
    __syncthreads();

    // RoPE on r
    float rf[8];
    #pragma unroll
    for (int j = 0; j < 8; ++j) {
        int nn = off + j;
        int nn2 = (nn + 32) & 63;
        float val = rbuf[h * 64 + nn] * rscale * ln_r[nn];
        float oth = rbuf[h * 64 + nn2] * rscale * ln_r[nn2];
        float rot = (nn < 32) ? -oth : oth;
        rf[j] = val * cosb[nn] + rot * sinb[nn];
    }
    // RoPE + first-mix on k
    float kfv[2];
    #pragma unroll
    for (int j = 0; j < 2; ++j) {
        int nn = ko2 + j;
        int nn2 = (nn + 32) & 63;
        float val = kbuf[kvh * 64 + nn] * kscale * ln_k[nn];
        float oth = kbuf[kvh * 64 + nn2] * kscale * ln_k[nn2];
        float rot = (nn < 32) ? -oth : oth;
        float kr = val * cosb[nn] + rot * sinb[nn];
        float gk = sigmf(smrow[6656 + kvh * 64 + nn] + k0b[kvh * 64 + nn]);
        kfv[j] = kr + (k_first[(size_t)bt * 512 + kvh * 64 + nn] - kr) * gk;
    }
    __syncthreads();
    kbuf[kidx] = kfv[0]; kbuf[kidx + 1] = kfv[1];
    float kn = kfv[0] * kfv[0] + kfv[1] * kfv[1];
    kn += __shfl_xor(kn, 1); kn += __shfl_xor(kn, 2); kn += __shfl_xor(kn, 4);
    kn += __shfl_xor(kn, 8); kn += __shfl_xor(kn, 16);
    if ((tid & 31) == 0) knorms[kvh] = fmaxf(sqrtf(kn), 1e-12f);
    __syncthreads();

    // stage 4: per-n scan-record assembly
    const float knv = knorms[h >> 2];
    char* scb = SC + ((size_t)(b * H_ + h) * T_ + t) * 896;
    __hip_bfloat16* us = (__hip_bfloat16*)scb;
    float* df = (float*)(scb + 640);
    float4 w1a = *(const float4*)(smrow + n0);
    float4 w1b = *(const float4*)(smrow + n0 + 4);
    float4 ara = *(const float4*)(smrow + 2048 + n0);
    float4 arb = *(const float4*)(smrow + 2048 + n0 + 4);
    float w1arr[8] = {w1a.x, w1a.y, w1a.z, w1a.w, w1b.x, w1b.y, w1b.z, w1b.w};
    float aarr[8] = {ara.x, ara.y, ara.z, ara.w, arb.x, arb.y, arb.z, arb.w};
    float bsum = 0.f;
    float vbl[8];
    #pragma unroll
    for (int j = 0; j < 8; ++j) {
        int nn = off + j, n = n0 + j;
        float w1 = w1arr[j] + w0[n];
        float w2v = -log1pf(expf(-w1)) - 0.5f;
        float av = sigmf(aarr[j] + a0[n]);
        float dec = expf(-expf(w2v));
        float kb = kbuf[(h >> 2) * 64 + nn];
        float vbv = vbuf[(h >> 2) * 64 + nn];
        float kkv = kb / knv;
        float ksc = kb * (1.f - w2v + av);
        us[nn]       = __float2bfloat16(rf[j]);
        us[64 + nn]  = __float2bfloat16(ksc);
        us[128 + nn] = __float2bfloat16(-kkv);
        us[192 + nn] = __float2bfloat16(kkv * av);
        us[256 + nn] = __float2bfloat16(vbv);
        df[nn] = dec;
        vbl[j] = vbv;
        bsum += rf[j] * ksc * r_k[h * 64 + nn];
    }
    float4 vv0 = {vbl[0], vbl[1], vbl[2], vbl[3]};
    float4 vv1 = {vbl[4], vbl[5], vbl[6], vbl[7]};
    *(float4*)(VB + (size_t)bt * HN_ + n0) = vv0;
    *(float4*)(VB + (size_t)bt * HN_ + n0 + 4) = vv1;
    bsum += __shfl_xor(bsum, 1); bsum += __shfl_xor(bsum, 2); bsum += __shfl_xor(bsum, 4);
    if ((tid & 7) == 0) SB[bt * H_ + h] = bsum;
}

// ---------------- sequential scan: one wave per (b,h), S row per lane ----------------
__global__ __launch_bounds__(64) void scan_kernel(const char* __restrict__ SC,
                                                  const float* __restrict__ state,
                                                  float* __restrict__ O) {
    const int bh = blockIdx.x;
    const int b = bh >> 5, h = bh & 31;
    const int lane = threadIdx.x;
    f32x2 S2[32];
    const float* srow = state + ((size_t)bh * 64 + lane) * 64;
    #pragma unroll
    for (int q = 0; q < 32; ++q) S2[q] = *(const f32x2*)(srow + 2 * q);
    __shared__ __align__(16) float sv[5][64]; // r, dec, ksc, aa, bb
    float* obase = O + (size_t)b * T_ * HN_ + h * 64 + lane;
    const char* base = SC + (size_t)bh * T_ * 896;
    float nr, ndec, nk, naa, nbb, nv;
    auto LOAD = [&](int t) {
        const __hip_bfloat16* us = (const __hip_bfloat16*)(base + (size_t)t * 896);
        const float* df = (const float*)(base + (size_t)t * 896 + 640);
        nr = __bfloat162float(us[lane]);
        nk = __bfloat162float(us[64 + lane]);
        naa = __bfloat162float(us[128 + lane]);
        nbb = __bfloat162float(us[192 + lane]);
        nv = __bfloat162float(us[256 + lane]);
        ndec = df[lane];
    };
    LOAD(0);
    for (int t = 0; t < T_; ++t) {
        sv[0][lane] = nr; sv[1][lane] = ndec; sv[2][lane] = nk; sv[3][lane] = naa; sv[4][lane] = nbb;
        float vt = nv;
        __syncthreads();
        if (t + 1 < T_) LOAD(t + 1);
        f32x2 sa0 = {0.f, 0.f}, sa1 = {0.f, 0.f};
        #pragma unroll
        for (int q = 0; q < 32; q += 2) {
            sa0 += S2[q] * *(const f32x2*)&sv[3][2 * q];
            sa1 += S2[q + 1] * *(const f32x2*)&sv[3][2 * q + 2];
        }
        float sa = sa0[0] + sa0[1] + sa1[0] + sa1[1];
        f32x2 sav = {sa, sa}, vtv = {vt, vt};
        f32x2 oa0 = {0.f, 0.f}, oa1 = {0.f, 0.f};
        #pragma unroll
        for (int q = 0; q < 32; q += 2) {
            {
                f32x2 dd = *(const f32x2*)&sv[1][2 * q];
                f32x2 kk2 = *(const f32x2*)&sv[2][2 * q];
                f32x2 bb2 = *(const f32x2*)&sv[4][2 * q];
                f32x2 rr2 = *(const f32x2*)&sv[0][2 * q];
                f32x2 Sn = S2[q] * dd + sav * bb2 + vtv * kk2;
                S2[q] = Sn;
                oa0 += Sn * rr2;
            }
            {
                f32x2 dd = *(const f32x2*)&sv[1][2 * q + 2];
                f32x2 kk2 = *(const f32x2*)&sv[2][2 * q + 2];
                f32x2 bb2 = *(const f32x2*)&sv[4][2 * q + 2];
                f32x2 rr2 = *(const f32x2*)&sv[0][2 * q + 2];
                f32x2 Sn = S2[q + 1] * dd + sav * bb2 + vtv * kk2;
                S2[q + 1] = Sn;
                oa1 += Sn * rr2;
            }
        }
        float o = (oa0[0] + oa0[1] + oa1[0] + oa1[1]) * 0.125f;
        obase[(size_t)t * HN_] = o;
        __syncthreads();
    }
}

// ---------------- post: U = (o + bonus_scalar*v) * g -> bf16 ----------------
__global__ void post_kernel(const float* __restrict__ O, const float* __restrict__ SB,
                            const float* __restrict__ VB, const float* __restrict__ SM,
                            __hip_bfloat16* __restrict__ Ub) {
    long i = (long)blockIdx.x * 256 + threadIdx.x;
    if (i >= (long)MTOK * HN_) return;
    int bt = (int)(i >> 11), n = (int)(i & 2047), h = n >> 6;
    float u = (O[i] + SB[bt * H_ + h] * VB[i]) * SM[(size_t)bt * SMN + 4608 + n];
    Ub[i] = __float2bfloat16(u);
}

extern "C" void kernel_launch(void* const* d_in, const int* in_sizes, int n_in,
                              void* d_out, int out_size, void* d_ws, size_t ws_size,
                              hipStream_t stream) {
    (void)in_sizes; (void)n_in; (void)out_size; (void)ws_size;
    const float* x_in    = (const float*)d_in[0];
    const float* v_first = (const float*)d_in[1];
    const float* k_first = (const float*)d_in[2];
    const float* state   = (const float*)d_in[3];
    const float* calc_cos= (const float*)d_in[4];
    const float* calc_sin= (const float*)d_in[5];
    const float* wavgk1  = (const float*)d_in[6];
    const float* w0      = (const float*)d_in[7];
    const float* w2      = (const float*)d_in[8];
    const float* a0      = (const float*)d_in[9];
    const float* a2      = (const float*)d_in[10];
    const float* v0      = (const float*)d_in[11];
    const float* v2      = (const float*)d_in[12];
    const float* g2      = (const float*)d_in[13];
    const float* k0      = (const float*)d_in[14];
    const float* k2      = (const float*)d_in[15];
    const float* r_k     = (const float*)d_in[16];
    const float* RKV_w   = (const float*)d_in[17];
    const float* O_w     = (const float*)d_in[18];
    const float* R_bias  = (const float*)d_in[19];
    const float* K_bias  = (const float*)d_in[20];
    const float* V_bias  = (const float*)d_in[21];
    const float* O_bias  = (const float*)d_in[22];
    const float* ln_r    = (const float*)d_in[23];
    const float* ln_k    = (const float*)d_in[24];
    const float* ln1     = (const float*)d_in[25];
    float* out = (float*)d_out;

    char* ws = (char*)d_ws;
    size_t off = 0;
    auto alloc = [&](size_t bytes) -> char* {
        char* p = ws + off;
        off = (off + bytes + 255) & ~(size_t)255;
        return p;
    };
    __hip_bfloat16* Xb     = (__hip_bfloat16*)alloc((size_t)MTOK * HN_ * 2);
    __hip_bfloat16* RKVb   = (__hip_bfloat16*)alloc((size_t)3072 * 2048 * 2);
    __hip_bfloat16* OWb    = (__hip_bfloat16*)alloc((size_t)2048 * 2048 * 2);
    __hip_bfloat16* WT1b   = (__hip_bfloat16*)alloc((size_t)320 * 2048 * 2);
    __hip_bfloat16* Wcatb  = (__hip_bfloat16*)alloc((size_t)SMN * KCAT * 2);
    __hip_bfloat16* XWmodb = (__hip_bfloat16*)alloc((size_t)MTOK * KCAT * 2);
    __hip_bfloat16* Ub     = (__hip_bfloat16*)alloc((size_t)MTOK * HN_ * 2);
    float* RKVf  = (float*)alloc((size_t)MTOK * 3072 * 4);
    float* XWraw = (float*)alloc((size_t)MTOK * KCAT * 4);
    float* SMf   = (float*)alloc((size_t)MTOK * SMN * 4);
    char*  SCb   = alloc((size_t)64 * T_ * 896);
    float* VBf   = (float*)alloc((size_t)MTOK * HN_ * 4);
    float* SBf   = (float*)alloc((size_t)MTOK * H_ * 4);
    float* Of    = (float*)alloc((size_t)MTOK * HN_ * 4);

    // weight prep
    f2b_kernel<<<(3072 * 2048 + 255) / 256, 256, 0, stream>>>(RKV_w, RKVb, 3072 * 2048);
    f2b_kernel<<<(2048 * 2048 + 255) / 256, 256, 0, stream>>>(O_w, OWb, 2048 * 2048);
    transpose_f2b_kernel<<<(320 * 2048 + 255) / 256, 256, 0, stream>>>(wavgk1, WT1b, 2048, 320);
    build_wcat_kernel<<<(SMN * KCAT + 255) / 256, 256, 0, stream>>>(w2, a2, v2, g2, k2, Wcatb);

    // x = rmsnorm(x_in, ln1) -> bf16
    rmsnorm_kernel<<<MTOK, 256, 0, stream>>>(x_in, ln1, Xb);

    // big GEMMs
    gemm_bt<<<dim3(3072 / 64, MTOK / 64), 256, 0, stream>>>(Xb, RKVb, RKVf, MTOK, 3072, 2048, nullptr, nullptr);
    gemm_bt<<<dim3(320 / 64, MTOK / 64), 256, 0, stream>>>(Xb, WT1b, XWraw, MTOK, 320, 2048, nullptr, nullptr);
    xwmod_kernel<<<(MTOK * KCAT + 255) / 256, 256, 0, stream>>>(XWraw, XWmodb);
    gemm_bt<<<dim3(SMN / 64, MTOK / 64), 256, 0, stream>>>(XWmodb, Wcatb, SMf, MTOK, SMN, KCAT, nullptr, nullptr);

    // compose scan records
    compose_kernel<<<MTOK, 256, 0, stream>>>(RKVf, SMf, v_first, k_first, calc_cos, calc_sin,
                                             R_bias, K_bias, V_bias, w0, a0, v0, k0,
                                             ln_r, ln_k, r_k, SCb, VBf, SBf);

    // sequential RWKV scan
    scan_kernel<<<64, 64, 0, stream>>>(SCb, state, Of);

    // post + output GEMM (adds x_in and O_bias in epilogue)
    post_kernel<<<(MTOK * HN_ + 255) / 256, 256, 0, stream>>>(Of, SBf, VBf, SMf, Ub);
    gemm_bt<<<dim3(HN_ / 64, MTOK / 64), 256, 0, stream>>>(Ub, OWb, out, MTOK, HN_, 2048, O_bias, x_in);
}

// Round 3
// 706.247 us; speedup vs baseline: 2.3950x; 2.3950x over previous
//
#include <hip/hip_runtime.h>
#include <hip/hip_bf16.h>

// Problem constants
#define B_ 2
#define T_ 1024
#define H_ 32
#define N_ 64
#define HN_ 2048
#define KVH_ 8
#define KVD_ 512
#define MTOK 2048        // B*T
#define SMN 7168         // concat small-gemm output width
#define KCAT 320
#define CH 64            // scan chunk length
#define NCH 16           // T/CH
#define NCHUNK 1024      // B*H*NCH

typedef __bf16 bf16x8 __attribute__((ext_vector_type(8)));
typedef float f32x4 __attribute__((ext_vector_type(4)));
typedef float f32x2 __attribute__((ext_vector_type(2)));

__device__ __forceinline__ float sigmf(float x) { return 1.f / (1.f + expf(-x)); }

// ---------------- prep kernels ----------------
__global__ void f2b_kernel(const float* __restrict__ in, __hip_bfloat16* __restrict__ out, int n) {
    int i = blockIdx.x * 256 + threadIdx.x;
    if (i < n) out[i] = __float2bfloat16(in[i]);
}

__global__ void transpose_f2b_kernel(const float* __restrict__ in, __hip_bfloat16* __restrict__ out,
                                     int rows, int cols) {
    long i = (long)blockIdx.x * 256 + threadIdx.x;
    if (i >= (long)rows * cols) return;
    int c = (int)(i / rows), r = (int)(i % rows);
    out[i] = __float2bfloat16(in[(size_t)r * cols + c]);
}

__global__ void build_wcat_kernel(const float* __restrict__ w2, const float* __restrict__ a2,
                                  const float* __restrict__ v2, const float* __restrict__ g2,
                                  const float* __restrict__ k2, __hip_bfloat16* __restrict__ out) {
    long i = (long)blockIdx.x * 256 + threadIdx.x;
    if (i >= (long)SMN * KCAT) return;
    int j = (int)(i / KCAT), k = (int)(i % KCAT);
    float v = 0.f;
    if (j < 2048)      { if (k < 64)             v = w2[(size_t)k * 2048 + j]; }
    else if (j < 4096) { if (k >= 64 && k < 128)  v = a2[(size_t)(k - 64) * 2048 + (j - 2048)]; }
    else if (j < 4608) { if (k >= 128 && k < 160) v = v2[(size_t)(k - 128) * 512 + (j - 4096)]; }
    else if (j < 6656) { if (k >= 160 && k < 288) v = g2[(size_t)(k - 160) * 2048 + (j - 4608)]; }
    else               { if (k >= 288)            v = k2[(size_t)(k - 288) * 512 + (j - 6656)]; }
    out[i] = __float2bfloat16(v);
}

// ---------------- RMSNorm over HN per token -> bf16 ----------------
__global__ __launch_bounds__(256) void rmsnorm_kernel(const float* __restrict__ x,
                                                      const float* __restrict__ ln1,
                                                      __hip_bfloat16* __restrict__ out) {
    const int bt = blockIdx.x, tid = threadIdx.x;
    const float* row = x + (size_t)bt * HN_;
    float4 v0 = *(const float4*)(row + tid * 8);
    float4 v1 = *(const float4*)(row + tid * 8 + 4);
    float s = v0.x*v0.x + v0.y*v0.y + v0.z*v0.z + v0.w*v0.w
            + v1.x*v1.x + v1.y*v1.y + v1.z*v1.z + v1.w*v1.w;
    for (int m = 1; m < 64; m <<= 1) s += __shfl_xor(s, m);
    __shared__ float red[4];
    if ((tid & 63) == 0) red[tid >> 6] = s;
    __syncthreads();
    s = red[0] + red[1] + red[2] + red[3];
    float scale = rsqrtf(s * (1.f / HN_) + 1e-6f);
    float vals[8] = {v0.x, v0.y, v0.z, v0.w, v1.x, v1.y, v1.z, v1.w};
    #pragma unroll
    for (int j = 0; j < 8; ++j)
        out[(size_t)bt * HN_ + tid * 8 + j] = __float2bfloat16(vals[j] * scale * ln1[tid * 8 + j]);
}

// ---------------- apply tanh/sigmoid to xw/xg segments -> bf16 ----------------
__global__ void xwmod_kernel(const float* __restrict__ in, __hip_bfloat16* __restrict__ out) {
    long i = (long)blockIdx.x * 256 + threadIdx.x;
    if (i >= (long)MTOK * KCAT) return;
    int c = (int)(i % KCAT);
    float x = in[i];
    if (c < 64) x = tanhf(x);
    else if (c >= 160 && c < 288) x = sigmf(x);
    out[i] = __float2bfloat16(x);
}

// ---------------- generic MFMA GEMM: C[M,N] = A[M,K] * B[N,K]^T (+bias +addend) ----------------
__global__ __launch_bounds__(256) void gemm_bt(const __hip_bfloat16* __restrict__ A,
                                               const __hip_bfloat16* __restrict__ B,
                                               float* __restrict__ C, int M, int N, int K,
                                               const float* __restrict__ bias,
                                               const float* __restrict__ addend) {
    __shared__ __align__(16) __hip_bfloat16 As[64][40];
    __shared__ __align__(16) __hip_bfloat16 Bs[64][40];
    const int tid = threadIdx.x;
    const int wave = tid >> 6, lane = tid & 63;
    const int wr = (wave >> 1) * 32, wc = (wave & 1) * 32;
    const int brow = blockIdx.y << 6, bcol = blockIdx.x << 6;
    const int lrow = tid >> 2, lcol = (tid & 3) << 3;
    const int fr = lane & 15, ko = (lane >> 4) << 3;
    f32x4 acc[2][2] = {};
    for (int k0 = 0; k0 < K; k0 += 32) {
        uint4 av = *(const uint4*)(A + (size_t)(brow + lrow) * K + k0 + lcol);
        uint4 bv = *(const uint4*)(B + (size_t)(bcol + lrow) * K + k0 + lcol);
        *(uint4*)(&As[lrow][lcol]) = av;
        *(uint4*)(&Bs[lrow][lcol]) = bv;
        __syncthreads();
        bf16x8 af0 = *(const bf16x8*)(&As[wr + fr][ko]);
        bf16x8 af1 = *(const bf16x8*)(&As[wr + 16 + fr][ko]);
        bf16x8 bf0 = *(const bf16x8*)(&Bs[wc + fr][ko]);
        bf16x8 bf1 = *(const bf16x8*)(&Bs[wc + 16 + fr][ko]);
        acc[0][0] = __builtin_amdgcn_mfma_f32_16x16x32_bf16(af0, bf0, acc[0][0], 0, 0, 0);
        acc[0][1] = __builtin_amdgcn_mfma_f32_16x16x32_bf16(af0, bf1, acc[0][1], 0, 0, 0);
        acc[1][0] = __builtin_amdgcn_mfma_f32_16x16x32_bf16(af1, bf0, acc[1][0], 0, 0, 0);
        acc[1][1] = __builtin_amdgcn_mfma_f32_16x16x32_bf16(af1, bf1, acc[1][1], 0, 0, 0);
        __syncthreads();
    }
    const int cr = (lane >> 4) << 2, cc = lane & 15;
    #pragma unroll
    for (int i = 0; i < 2; ++i)
        #pragma unroll
        for (int j = 0; j < 2; ++j)
            #pragma unroll
            for (int r = 0; r < 4; ++r) {
                int row = brow + wr + i * 16 + cr + r;
                int col = bcol + wc + j * 16 + cc;
                float v = acc[i][j][r];
                if (bias) v += bias[col];
                if (addend) v += addend[(size_t)row * N + col];
                C[(size_t)row * N + col] = v;
            }
}

// ---------------- compose: per-token head math -> packed scan records ----------------
// record per (bh,t): 896B = bf16[5][64] {r, ksc, aa, bb, v} + f32[64] dec
__global__ __launch_bounds__(256) void compose_kernel(
    const float* __restrict__ RKV, const float* __restrict__ SM,
    const float* __restrict__ v_first, const float* __restrict__ k_first,
    const float* __restrict__ cosd, const float* __restrict__ sind,
    const float* __restrict__ R_bias, const float* __restrict__ K_bias,
    const float* __restrict__ V_bias, const float* __restrict__ w0,
    const float* __restrict__ a0, const float* __restrict__ v0b,
    const float* __restrict__ k0b, const float* __restrict__ ln_r,
    const float* __restrict__ ln_k, const float* __restrict__ r_k,
    char* __restrict__ SC, __hip_bfloat16* __restrict__ VB, float* __restrict__ SB) {
    __shared__ __align__(16) float rbuf[HN_];
    __shared__ __align__(16) float kbuf[KVD_];
    __shared__ __align__(16) float vbuf[KVD_];
    __shared__ float knorms[KVH_];
    __shared__ float cosb[64], sinb[64];
    const int bt = blockIdx.x;
    const int b = bt >> 10, t = bt & 1023;
    const int tid = threadIdx.x;
    const float* rkvrow = RKV + (size_t)bt * 3072;
    const float* smrow = SM + (size_t)bt * SMN;

    if (tid < 64) {
        cosb[tid] = cosd[(size_t)bt * 64 + tid];
        sinb[tid] = sind[(size_t)bt * 64 + tid];
    }

    const int h = tid >> 3;
    const int off = (tid & 7) << 3;
    const int n0 = tid << 3;
    float rraw[8];
    {
        float4 x0 = *(const float4*)(rkvrow + n0);
        float4 x1 = *(const float4*)(rkvrow + n0 + 4);
        float4 b0 = *(const float4*)(R_bias + n0);
        float4 b1 = *(const float4*)(R_bias + n0 + 4);
        rraw[0] = x0.x + b0.x; rraw[1] = x0.y + b0.y; rraw[2] = x0.z + b0.z; rraw[3] = x0.w + b0.w;
        rraw[4] = x1.x + b1.x; rraw[5] = x1.y + b1.y; rraw[6] = x1.z + b1.z; rraw[7] = x1.w + b1.w;
    }
    float rss = 0.f;
    #pragma unroll
    for (int j = 0; j < 8; ++j) { rss += rraw[j] * rraw[j]; rbuf[n0 + j] = rraw[j]; }
    rss += __shfl_xor(rss, 1); rss += __shfl_xor(rss, 2); rss += __shfl_xor(rss, 4);
    float rscale = rsqrtf(rss * (1.f / 64.f) + 1e-6f);

    const int kvh = tid >> 5;
    const int ko2 = (tid & 31) << 1;
    const int kidx = kvh * 64 + ko2;
    float kraw0 = rkvrow[2048 + kidx] + K_bias[kidx];
    float kraw1 = rkvrow[2048 + kidx + 1] + K_bias[kidx + 1];
    float kss = kraw0 * kraw0 + kraw1 * kraw1;
    kss += __shfl_xor(kss, 1); kss += __shfl_xor(kss, 2); kss += __shfl_xor(kss, 4);
    kss += __shfl_xor(kss, 8); kss += __shfl_xor(kss, 16);
    float kscale = rsqrtf(kss * (1.f / 64.f) + 1e-6f);
    kbuf[kidx] = kraw0; kbuf[kidx + 1] = kraw1;

    {
        float va = rkvrow[2560 + kidx] + V_bias[kidx];
        float vb2 = rkvrow[2560 + kidx + 1] + V_bias[kidx + 1];
        float gv0 = sigmf(smrow[4096 + kidx] + v0b[kidx]);
        float gv1 = sigmf(smrow[4096 + kidx + 1] + v0b[kidx + 1]);
        vbuf[kidx] = va + (v_first[(size_t)bt * 512 + kidx] - va) * gv0;
        vbuf[kidx + 1] = vb2 + (v_first[(size_t)bt * 512 + kidx + 1] - vb2) * gv1;
    }
    __syncthreads();

    float rf[8];
    #pragma unroll
    for (int j = 0; j < 8; ++j) {
        int nn = off + j;
        int nn2 = (nn + 32) & 63;
        float val = rbuf[h * 64 + nn] * rscale * ln_r[nn];
        float oth = rbuf[h * 64 + nn2] * rscale * ln_r[nn2];
        float rot = (nn < 32) ? -oth : oth;
        rf[j] = val * cosb[nn] + rot * sinb[nn];
    }
    float kfv[2];
    #pragma unroll
    for (int j = 0; j < 2; ++j) {
        int nn = ko2 + j;
        int nn2 = (nn + 32) & 63;
        float val = kbuf[kvh * 64 + nn] * kscale * ln_k[nn];
        float oth = kbuf[kvh * 64 + nn2] * kscale * ln_k[nn2];
        float rot = (nn < 32) ? -oth : oth;
        float kr = val * cosb[nn] + rot * sinb[nn];
        float gk = sigmf(smrow[6656 + kvh * 64 + nn] + k0b[kvh * 64 + nn]);
        kfv[j] = kr + (k_first[(size_t)bt * 512 + kvh * 64 + nn] - kr) * gk;
    }
    __syncthreads();
    kbuf[kidx] = kfv[0]; kbuf[kidx + 1] = kfv[1];
    float kn = kfv[0] * kfv[0] + kfv[1] * kfv[1];
    kn += __shfl_xor(kn, 1); kn += __shfl_xor(kn, 2); kn += __shfl_xor(kn, 4);
    kn += __shfl_xor(kn, 8); kn += __shfl_xor(kn, 16);
    if ((tid & 31) == 0) knorms[kvh] = fmaxf(sqrtf(kn), 1e-12f);
    __syncthreads();

    const float knv = knorms[h >> 2];
    char* scb = SC + ((size_t)(b * H_ + h) * T_ + t) * 896;
    __hip_bfloat16* us = (__hip_bfloat16*)scb;
    float* df = (float*)(scb + 640);
    float4 w1a = *(const float4*)(smrow + n0);
    float4 w1b = *(const float4*)(smrow + n0 + 4);
    float4 ara = *(const float4*)(smrow + 2048 + n0);
    float4 arb = *(const float4*)(smrow + 2048 + n0 + 4);
    float w1arr[8] = {w1a.x, w1a.y, w1a.z, w1a.w, w1b.x, w1b.y, w1b.z, w1b.w};
    float aarr[8] = {ara.x, ara.y, ara.z, ara.w, arb.x, arb.y, arb.z, arb.w};
    float bsum = 0.f;
    #pragma unroll
    for (int j = 0; j < 8; ++j) {
        int nn = off + j, n = n0 + j;
        float w1 = w1arr[j] + w0[n];
        float w2v = -log1pf(expf(-w1)) - 0.5f;
        float av = sigmf(aarr[j] + a0[n]);
        float dec = expf(-expf(w2v));
        float kb = kbuf[(h >> 2) * 64 + nn];
        float vbv = vbuf[(h >> 2) * 64 + nn];
        float kkv = kb / knv;
        float ksc = kb * (1.f - w2v + av);
        us[nn]       = __float2bfloat16(rf[j]);
        us[64 + nn]  = __float2bfloat16(ksc);
        us[128 + nn] = __float2bfloat16(-kkv);
        us[192 + nn] = __float2bfloat16(kkv * av);
        us[256 + nn] = __float2bfloat16(vbv);
        df[nn] = dec;
        VB[(size_t)bt * HN_ + n] = __float2bfloat16(vbv);
        bsum += rf[j] * ksc * r_k[h * 64 + nn];
    }
    bsum += __shfl_xor(bsum, 1); bsum += __shfl_xor(bsum, 2); bsum += __shfl_xor(bsum, 4);
    if ((tid & 7) == 0) SB[bt * H_ + h] = bsum;
}

// ---------------- chunked scan pass 1: per-chunk P, S_loc, q_t, oloc_t(->O) ----------------
__global__ __launch_bounds__(64, 2) void scan_pass1(
    const char* __restrict__ SC, float* __restrict__ Q, float* __restrict__ O,
    float* __restrict__ Pf, float* __restrict__ Sf) {
    const int chunk = blockIdx.x;
    const int bh = chunk >> 4, c = chunk & 15;
    const int b = bh >> 5, h = bh & 31;
    const int lane = threadIdx.x;
    const char* base = SC + ((size_t)bh * T_ + (size_t)c * CH) * 896;

    f32x4 P4[16], S4[16];
    #pragma unroll
    for (int j = 0; j < 16; ++j) {
        #pragma unroll
        for (int e = 0; e < 4; ++e) {
            P4[j][e] = (4 * j + e == lane) ? 1.f : 0.f;
            S4[j][e] = 0.f;
        }
    }
    __shared__ __align__(16) float ld[2][5][64];
    float pr_r, pr_k, pr_a, pr_b, pr_v, pr_d;
    auto LOADT = [&](int t) {
        const __hip_bfloat16* us = (const __hip_bfloat16*)(base + (size_t)t * 896);
        pr_r = __bfloat162float(us[lane]);
        pr_k = __bfloat162float(us[64 + lane]);
        pr_a = __bfloat162float(us[128 + lane]);
        pr_b = __bfloat162float(us[192 + lane]);
        pr_v = __bfloat162float(us[256 + lane]);
        pr_d = *(const float*)(base + (size_t)t * 896 + 640 + 4 * lane);
    };
    LOADT(0);
    float* qbase = Q + (size_t)chunk * CH * 64 + lane;
    float* obase = O + ((size_t)b * T_ + (size_t)c * CH) * HN_ + h * 64 + lane;
    for (int t = 0; t < CH; ++t) {
        const int buf = t & 1;
        const float vt = pr_v;
        ld[buf][0][lane] = pr_a;
        ld[buf][1][lane] = pr_b;
        ld[buf][2][lane] = pr_d;
        ld[buf][3][lane] = pr_k;
        ld[buf][4][lane] = pr_r;
        __syncthreads();
        if (t + 1 < CH) LOADT(t + 1);
        f32x4 cp4 = {0,0,0,0}, sa4 = {0,0,0,0};
        #pragma unroll
        for (int j = 0; j < 16; ++j) {
            f32x4 a4 = *(const f32x4*)&ld[buf][0][4 * j];
            cp4 += P4[j] * a4;
            sa4 += S4[j] * a4;
        }
        const float cP = cp4[0] + cp4[1] + cp4[2] + cp4[3];
        const float sa = sa4[0] + sa4[1] + sa4[2] + sa4[3];
        const f32x4 cPv = {cP, cP, cP, cP}, sav = {sa, sa, sa, sa}, vtv = {vt, vt, vt, vt};
        f32x4 q4 = {0,0,0,0}, ol4 = {0,0,0,0};
        #pragma unroll
        for (int j = 0; j < 16; ++j) {
            f32x4 d4 = *(const f32x4*)&ld[buf][2][4 * j];
            f32x4 b4 = *(const f32x4*)&ld[buf][1][4 * j];
            f32x4 k4 = *(const f32x4*)&ld[buf][3][4 * j];
            f32x4 r4 = *(const f32x4*)&ld[buf][4][4 * j];
            f32x4 Pn = P4[j] * d4 + cPv * b4;
            f32x4 Sn = S4[j] * d4 + sav * b4 + vtv * k4;
            P4[j] = Pn; S4[j] = Sn;
            q4 += Pn * r4;
            ol4 += Sn * r4;
        }
        qbase[(size_t)t * 64] = q4[0] + q4[1] + q4[2] + q4[3];
        obase[(size_t)t * HN_] = ol4[0] + ol4[1] + ol4[2] + ol4[3];  // oloc, unscaled
        __syncthreads();
    }
    float* pf = Pf + (size_t)chunk * 4096 + lane * 64;
    float* sf = Sf + (size_t)chunk * 4096 + lane * 64;
    #pragma unroll
    for (int j = 0; j < 16; ++j) {
        *(f32x4*)(pf + 4 * j) = P4[j];
        *(f32x4*)(sf + 4 * j) = S4[j];
    }
}

// ---------------- pass 2: propagate chunk-initial states (Sf -> Sinit in place) ----------------
__global__ __launch_bounds__(256) void scan_pass2(
    const float* __restrict__ Pf, float* __restrict__ Sf, const float* __restrict__ state) {
    const int bh = blockIdx.x;
    const int tid = threadIdx.x;
    const int v = tid >> 2, cs = (tid & 3) << 4;
    __shared__ __align__(16) float S[64][68];
    #pragma unroll
    for (int j = 0; j < 16; j += 4)
        *(f32x4*)&S[v][cs + j] = *(const f32x4*)&state[((size_t)bh * 64 + v) * 64 + cs + j];
    __syncthreads();
    for (int c = 0; c < NCH; ++c) {
        const size_t ck = (size_t)(bh * NCH + c) * 4096;
        f32x4 acc[4], cur[4];
        #pragma unroll
        for (int j = 0; j < 4; ++j) {
            acc[j] = *(const f32x4*)&Sf[ck + (size_t)v * 64 + cs + 4 * j];
            cur[j] = *(const f32x4*)&S[v][cs + 4 * j];
        }
        #pragma unroll
        for (int j = 0; j < 4; ++j)
            *(f32x4*)&Sf[ck + (size_t)v * 64 + cs + 4 * j] = cur[j];   // Sinit(c) := S
        float row[64];
        #pragma unroll
        for (int j = 0; j < 16; ++j)
            *(f32x4*)&row[4 * j] = *(const f32x4*)&S[v][4 * j];
        #pragma unroll 8
        for (int k = 0; k < 64; ++k) {
            const float* pr = Pf + ck + (size_t)k * 64 + cs;
            f32x4 p0 = *(const f32x4*)(pr);
            f32x4 p1 = *(const f32x4*)(pr + 4);
            f32x4 p2 = *(const f32x4*)(pr + 8);
            f32x4 p3 = *(const f32x4*)(pr + 12);
            f32x4 sk = {row[k], row[k], row[k], row[k]};
            acc[0] += sk * p0; acc[1] += sk * p1; acc[2] += sk * p2; acc[3] += sk * p3;
        }
        __syncthreads();
        #pragma unroll
        for (int j = 0; j < 4; ++j)
            *(f32x4*)&S[v][cs + 4 * j] = acc[j];
        __syncthreads();
    }
}

// ---------------- pass 3: O[t] = (Sinit · q_t + oloc_t) * N^-0.5, in place ----------------
__global__ __launch_bounds__(64) void scan_pass3(
    const float* __restrict__ Q, const float* __restrict__ Sinit, float* __restrict__ O) {
    const int chunk = blockIdx.x;
    const int bh = chunk >> 4, c = chunk & 15;
    const int b = bh >> 5, h = bh & 31;
    const int t = threadIdx.x;
    __shared__ __align__(16) float S[64][64];
    #pragma unroll
    for (int j = 0; j < 16; ++j)
        *(f32x4*)&S[t][4 * j] = *(const f32x4*)&Sinit[(size_t)chunk * 4096 + (size_t)t * 64 + 4 * j];
    __syncthreads();
    float q[64];
    #pragma unroll
    for (int j = 0; j < 16; ++j)
        *(f32x4*)&q[4 * j] = *(const f32x4*)&Q[((size_t)chunk * CH + t) * 64 + 4 * j];
    float* orow = O + ((size_t)b * T_ + (size_t)c * CH + t) * HN_ + h * 64;
    #pragma unroll 4
    for (int v = 0; v < 64; ++v) {
        f32x4 a = {0, 0, 0, 0};
        #pragma unroll
        for (int j = 0; j < 16; ++j)
            a += *(const f32x4*)&S[v][4 * j] * *(const f32x4*)&q[4 * j];
        orow[v] = (a[0] + a[1] + a[2] + a[3] + orow[v]) * 0.125f;
    }
}

// ---------------- post: U = (o + bonus_scalar*v) * g -> bf16 ----------------
__global__ void post_kernel(const float* __restrict__ O, const float* __restrict__ SB,
                            const __hip_bfloat16* __restrict__ VB, const float* __restrict__ SM,
                            __hip_bfloat16* __restrict__ Ub) {
    long i = (long)blockIdx.x * 256 + threadIdx.x;
    if (i >= (long)MTOK * HN_) return;
    int bt = (int)(i >> 11), n = (int)(i & 2047), h = n >> 6;
    float u = (O[i] + SB[bt * H_ + h] * __bfloat162float(VB[i])) * SM[(size_t)bt * SMN + 4608 + n];
    Ub[i] = __float2bfloat16(u);
}

extern "C" void kernel_launch(void* const* d_in, const int* in_sizes, int n_in,
                              void* d_out, int out_size, void* d_ws, size_t ws_size,
                              hipStream_t stream) {
    (void)in_sizes; (void)n_in; (void)out_size; (void)ws_size;
    const float* x_in    = (const float*)d_in[0];
    const float* v_first = (const float*)d_in[1];
    const float* k_first = (const float*)d_in[2];
    const float* state   = (const float*)d_in[3];
    const float* calc_cos= (const float*)d_in[4];
    const float* calc_sin= (const float*)d_in[5];
    const float* wavgk1  = (const float*)d_in[6];
    const float* w0      = (const float*)d_in[7];
    const float* w2      = (const float*)d_in[8];
    const float* a0      = (const float*)d_in[9];
    const float* a2      = (const float*)d_in[10];
    const float* v0      = (const float*)d_in[11];
    const float* v2      = (const float*)d_in[12];
    const float* g2      = (const float*)d_in[13];
    const float* k0      = (const float*)d_in[14];
    const float* k2      = (const float*)d_in[15];
    const float* r_k     = (const float*)d_in[16];
    const float* RKV_w   = (const float*)d_in[17];
    const float* O_w     = (const float*)d_in[18];
    const float* R_bias  = (const float*)d_in[19];
    const float* K_bias  = (const float*)d_in[20];
    const float* V_bias  = (const float*)d_in[21];
    const float* O_bias  = (const float*)d_in[22];
    const float* ln_r    = (const float*)d_in[23];
    const float* ln_k    = (const float*)d_in[24];
    const float* ln1     = (const float*)d_in[25];
    float* out = (float*)d_out;

    char* ws = (char*)d_ws;
    size_t off = 0;
    auto alloc = [&](size_t bytes) -> char* {
        char* p = ws + off;
        off = (off + bytes + 255) & ~(size_t)255;
        return p;
    };
    // ---- persistent region (~151 MB) ----
    float* SMf = (float*)alloc((size_t)MTOK * SMN * 4);               // gemm3 -> post
    char*  SCb = alloc((size_t)64 * T_ * 896);                        // compose -> pass1
    __hip_bfloat16* Ub = (__hip_bfloat16*)SCb;                        // aliases SCb (post -> final gemm)
    __hip_bfloat16* VBb = (__hip_bfloat16*)alloc((size_t)MTOK * HN_ * 2); // compose -> post
    float* SBf = (float*)alloc((size_t)MTOK * H_ * 4);                // compose -> post
    float* Of  = (float*)alloc((size_t)MTOK * HN_ * 4);               // pass1 -> post
    __hip_bfloat16* OWb = (__hip_bfloat16*)alloc((size_t)2048 * 2048 * 2); // prep -> final gemm

    // ---- overlapped region: stage A (pre-scan, ~56 MB) ----
    size_t ovl = off;
    __hip_bfloat16* Xb     = (__hip_bfloat16*)alloc((size_t)MTOK * HN_ * 2);
    __hip_bfloat16* RKVb   = (__hip_bfloat16*)alloc((size_t)3072 * 2048 * 2);
    __hip_bfloat16* WT1b   = (__hip_bfloat16*)alloc((size_t)320 * 2048 * 2);
    __hip_bfloat16* Wcatb  = (__hip_bfloat16*)alloc((size_t)SMN * KCAT * 2);
    __hip_bfloat16* XWmodb = (__hip_bfloat16*)alloc((size_t)MTOK * KCAT * 2);
    float* RKVf  = (float*)alloc((size_t)MTOK * 3072 * 4);
    float* XWraw = (float*)alloc((size_t)MTOK * KCAT * 4);
    // ---- overlapped region: stage B (scan, ~50 MB) — reuses stage A space ----
    off = ovl;
    float* Qf  = (float*)alloc((size_t)NCHUNK * CH * 64 * 4);         // pass1 -> pass3
    float* Pff = (float*)alloc((size_t)NCHUNK * 4096 * 4);            // pass1 -> pass2
    float* Sff = (float*)alloc((size_t)NCHUNK * 4096 * 4);            // pass1 -> pass3

    // weight prep
    f2b_kernel<<<(3072 * 2048 + 255) / 256, 256, 0, stream>>>(RKV_w, RKVb, 3072 * 2048);
    f2b_kernel<<<(2048 * 2048 + 255) / 256, 256, 0, stream>>>(O_w, OWb, 2048 * 2048);
    transpose_f2b_kernel<<<(320 * 2048 + 255) / 256, 256, 0, stream>>>(wavgk1, WT1b, 2048, 320);
    build_wcat_kernel<<<(SMN * KCAT + 255) / 256, 256, 0, stream>>>(w2, a2, v2, g2, k2, Wcatb);

    // x = rmsnorm(x_in, ln1) -> bf16
    rmsnorm_kernel<<<MTOK, 256, 0, stream>>>(x_in, ln1, Xb);

    // big GEMMs
    gemm_bt<<<dim3(3072 / 64, MTOK / 64), 256, 0, stream>>>(Xb, RKVb, RKVf, MTOK, 3072, 2048, nullptr, nullptr);
    gemm_bt<<<dim3(320 / 64, MTOK / 64), 256, 0, stream>>>(Xb, WT1b, XWraw, MTOK, 320, 2048, nullptr, nullptr);
    xwmod_kernel<<<(MTOK * KCAT + 255) / 256, 256, 0, stream>>>(XWraw, XWmodb);
    gemm_bt<<<dim3(SMN / 64, MTOK / 64), 256, 0, stream>>>(XWmodb, Wcatb, SMf, MTOK, SMN, KCAT, nullptr, nullptr);

    // compose scan records
    compose_kernel<<<MTOK, 256, 0, stream>>>(RKVf, SMf, v_first, k_first, calc_cos, calc_sin,
                                             R_bias, K_bias, V_bias, w0, a0, v0, k0,
                                             ln_r, ln_k, r_k, SCb, VBb, SBf);

    // chunked RWKV scan: pass1 (parallel) -> pass2 (chunk-sequential) -> pass3 (parallel)
    scan_pass1<<<NCHUNK, 64, 0, stream>>>(SCb, Qf, Of, Pff, Sff);
    scan_pass2<<<B_ * H_, 256, 0, stream>>>(Pff, Sff, state);
    scan_pass3<<<NCHUNK, 64, 0, stream>>>(Qf, Sff, Of);

    // post + output GEMM (adds x_in and O_bias in epilogue)
    post_kernel<<<(MTOK * HN_ + 255) / 256, 256, 0, stream>>>(Of, SBf, VBb, SMf, Ub);
    gemm_bt<<<dim3(HN_ / 64, MTOK / 64), 256, 0, stream>>>(Ub, OWb, out, MTOK, HN_, 2048, O_bias, x_in);
}

// Round 4
// 452.923 us; speedup vs baseline: 3.7345x; 1.5593x over previous
//
#include <hip/hip_runtime.h>
#include <hip/hip_bf16.h>

// Problem constants
#define B_ 2
#define T_ 1024
#define H_ 32
#define N_ 64
#define HN_ 2048
#define KVH_ 8
#define KVD_ 512
#define MTOK 2048        // B*T
#define SMN 7168         // concat small-gemm output width
#define KCAT 320
#define CH 64            // scan chunk length
#define NCH 16           // T/CH
#define NCHUNK 1024      // B*H*NCH

typedef __bf16 bf16x8 __attribute__((ext_vector_type(8)));
typedef float f32x4 __attribute__((ext_vector_type(4)));
typedef float f32x2 __attribute__((ext_vector_type(2)));

__device__ __forceinline__ float sigmf(float x) { return 1.f / (1.f + expf(-x)); }

// ---------------- prep kernels ----------------
__global__ void f2b_kernel(const float* __restrict__ in, __hip_bfloat16* __restrict__ out, int n) {
    int i = blockIdx.x * 256 + threadIdx.x;
    if (i < n) out[i] = __float2bfloat16(in[i]);
}

__global__ void transpose_f2b_kernel(const float* __restrict__ in, __hip_bfloat16* __restrict__ out,
                                     int rows, int cols) {
    long i = (long)blockIdx.x * 256 + threadIdx.x;
    if (i >= (long)rows * cols) return;
    int c = (int)(i / rows), r = (int)(i % rows);
    out[i] = __float2bfloat16(in[(size_t)r * cols + c]);
}

__global__ void build_wcat_kernel(const float* __restrict__ w2, const float* __restrict__ a2,
                                  const float* __restrict__ v2, const float* __restrict__ g2,
                                  const float* __restrict__ k2, __hip_bfloat16* __restrict__ out) {
    long i = (long)blockIdx.x * 256 + threadIdx.x;
    if (i >= (long)SMN * KCAT) return;
    int j = (int)(i / KCAT), k = (int)(i % KCAT);
    float v = 0.f;
    if (j < 2048)      { if (k < 64)             v = w2[(size_t)k * 2048 + j]; }
    else if (j < 4096) { if (k >= 64 && k < 128)  v = a2[(size_t)(k - 64) * 2048 + (j - 2048)]; }
    else if (j < 4608) { if (k >= 128 && k < 160) v = v2[(size_t)(k - 128) * 512 + (j - 4096)]; }
    else if (j < 6656) { if (k >= 160 && k < 288) v = g2[(size_t)(k - 160) * 2048 + (j - 4608)]; }
    else               { if (k >= 288)            v = k2[(size_t)(k - 288) * 512 + (j - 6656)]; }
    out[i] = __float2bfloat16(v);
}

// ---------------- RMSNorm over HN per token -> bf16 ----------------
__global__ __launch_bounds__(256) void rmsnorm_kernel(const float* __restrict__ x,
                                                      const float* __restrict__ ln1,
                                                      __hip_bfloat16* __restrict__ out) {
    const int bt = blockIdx.x, tid = threadIdx.x;
    const float* row = x + (size_t)bt * HN_;
    float4 v0 = *(const float4*)(row + tid * 8);
    float4 v1 = *(const float4*)(row + tid * 8 + 4);
    float s = v0.x*v0.x + v0.y*v0.y + v0.z*v0.z + v0.w*v0.w
            + v1.x*v1.x + v1.y*v1.y + v1.z*v1.z + v1.w*v1.w;
    for (int m = 1; m < 64; m <<= 1) s += __shfl_xor(s, m);
    __shared__ float red[4];
    if ((tid & 63) == 0) red[tid >> 6] = s;
    __syncthreads();
    s = red[0] + red[1] + red[2] + red[3];
    float scale = rsqrtf(s * (1.f / HN_) + 1e-6f);
    float vals[8] = {v0.x, v0.y, v0.z, v0.w, v1.x, v1.y, v1.z, v1.w};
    #pragma unroll
    for (int j = 0; j < 8; ++j)
        out[(size_t)bt * HN_ + tid * 8 + j] = __float2bfloat16(vals[j] * scale * ln1[tid * 8 + j]);
}

// ---------------- apply tanh/sigmoid to xw/xg segments -> bf16 ----------------
__global__ void xwmod_kernel(const float* __restrict__ in, __hip_bfloat16* __restrict__ out) {
    long i = (long)blockIdx.x * 256 + threadIdx.x;
    if (i >= (long)MTOK * KCAT) return;
    int c = (int)(i % KCAT);
    float x = in[i];
    if (c < 64) x = tanhf(x);
    else if (c >= 160 && c < 288) x = sigmf(x);
    out[i] = __float2bfloat16(x);
}

// ---------------- generic MFMA GEMM: C[M,N] = A[M,K] * B[N,K]^T (+bias +addend) ----------------
__global__ __launch_bounds__(256) void gemm_bt(const __hip_bfloat16* __restrict__ A,
                                               const __hip_bfloat16* __restrict__ B,
                                               float* __restrict__ C, int M, int N, int K,
                                               const float* __restrict__ bias,
                                               const float* __restrict__ addend) {
    __shared__ __align__(16) __hip_bfloat16 As[64][40];
    __shared__ __align__(16) __hip_bfloat16 Bs[64][40];
    const int tid = threadIdx.x;
    const int wave = tid >> 6, lane = tid & 63;
    const int wr = (wave >> 1) * 32, wc = (wave & 1) * 32;
    const int brow = blockIdx.y << 6, bcol = blockIdx.x << 6;
    const int lrow = tid >> 2, lcol = (tid & 3) << 3;
    const int fr = lane & 15, ko = (lane >> 4) << 3;
    f32x4 acc[2][2] = {};
    for (int k0 = 0; k0 < K; k0 += 32) {
        uint4 av = *(const uint4*)(A + (size_t)(brow + lrow) * K + k0 + lcol);
        uint4 bv = *(const uint4*)(B + (size_t)(bcol + lrow) * K + k0 + lcol);
        *(uint4*)(&As[lrow][lcol]) = av;
        *(uint4*)(&Bs[lrow][lcol]) = bv;
        __syncthreads();
        bf16x8 af0 = *(const bf16x8*)(&As[wr + fr][ko]);
        bf16x8 af1 = *(const bf16x8*)(&As[wr + 16 + fr][ko]);
        bf16x8 bf0 = *(const bf16x8*)(&Bs[wc + fr][ko]);
        bf16x8 bf1 = *(const bf16x8*)(&Bs[wc + 16 + fr][ko]);
        acc[0][0] = __builtin_amdgcn_mfma_f32_16x16x32_bf16(af0, bf0, acc[0][0], 0, 0, 0);
        acc[0][1] = __builtin_amdgcn_mfma_f32_16x16x32_bf16(af0, bf1, acc[0][1], 0, 0, 0);
        acc[1][0] = __builtin_amdgcn_mfma_f32_16x16x32_bf16(af1, bf0, acc[1][0], 0, 0, 0);
        acc[1][1] = __builtin_amdgcn_mfma_f32_16x16x32_bf16(af1, bf1, acc[1][1], 0, 0, 0);
        __syncthreads();
    }
    const int cr = (lane >> 4) << 2, cc = lane & 15;
    #pragma unroll
    for (int i = 0; i < 2; ++i)
        #pragma unroll
        for (int j = 0; j < 2; ++j)
            #pragma unroll
            for (int r = 0; r < 4; ++r) {
                int row = brow + wr + i * 16 + cr + r;
                int col = bcol + wc + j * 16 + cc;
                float v = acc[i][j][r];
                if (bias) v += bias[col];
                if (addend) v += addend[(size_t)row * N + col];
                C[(size_t)row * N + col] = v;
            }
}

// ---------------- compose: per-token head math -> packed scan records ----------------
// record per (bh,t): 896B = bf16[5][64] {r, ksc, aa, bb, v} + f32[64] dec
__global__ __launch_bounds__(256) void compose_kernel(
    const float* __restrict__ RKV, const float* __restrict__ SM,
    const float* __restrict__ v_first, const float* __restrict__ k_first,
    const float* __restrict__ cosd, const float* __restrict__ sind,
    const float* __restrict__ R_bias, const float* __restrict__ K_bias,
    const float* __restrict__ V_bias, const float* __restrict__ w0,
    const float* __restrict__ a0, const float* __restrict__ v0b,
    const float* __restrict__ k0b, const float* __restrict__ ln_r,
    const float* __restrict__ ln_k, const float* __restrict__ r_k,
    char* __restrict__ SC, __hip_bfloat16* __restrict__ VB, float* __restrict__ SB) {
    __shared__ __align__(16) float rbuf[HN_];
    __shared__ __align__(16) float kbuf[KVD_];
    __shared__ __align__(16) float vbuf[KVD_];
    __shared__ float knorms[KVH_];
    __shared__ float cosb[64], sinb[64];
    const int bt = blockIdx.x;
    const int b = bt >> 10, t = bt & 1023;
    const int tid = threadIdx.x;
    const float* rkvrow = RKV + (size_t)bt * 3072;
    const float* smrow = SM + (size_t)bt * SMN;

    if (tid < 64) {
        cosb[tid] = cosd[(size_t)bt * 64 + tid];
        sinb[tid] = sind[(size_t)bt * 64 + tid];
    }

    const int h = tid >> 3;
    const int off = (tid & 7) << 3;
    const int n0 = tid << 3;
    float rraw[8];
    {
        float4 x0 = *(const float4*)(rkvrow + n0);
        float4 x1 = *(const float4*)(rkvrow + n0 + 4);
        float4 b0 = *(const float4*)(R_bias + n0);
        float4 b1 = *(const float4*)(R_bias + n0 + 4);
        rraw[0] = x0.x + b0.x; rraw[1] = x0.y + b0.y; rraw[2] = x0.z + b0.z; rraw[3] = x0.w + b0.w;
        rraw[4] = x1.x + b1.x; rraw[5] = x1.y + b1.y; rraw[6] = x1.z + b1.z; rraw[7] = x1.w + b1.w;
    }
    float rss = 0.f;
    #pragma unroll
    for (int j = 0; j < 8; ++j) { rss += rraw[j] * rraw[j]; rbuf[n0 + j] = rraw[j]; }
    rss += __shfl_xor(rss, 1); rss += __shfl_xor(rss, 2); rss += __shfl_xor(rss, 4);
    float rscale = rsqrtf(rss * (1.f / 64.f) + 1e-6f);

    const int kvh = tid >> 5;
    const int ko2 = (tid & 31) << 1;
    const int kidx = kvh * 64 + ko2;
    float kraw0 = rkvrow[2048 + kidx] + K_bias[kidx];
    float kraw1 = rkvrow[2048 + kidx + 1] + K_bias[kidx + 1];
    float kss = kraw0 * kraw0 + kraw1 * kraw1;
    kss += __shfl_xor(kss, 1); kss += __shfl_xor(kss, 2); kss += __shfl_xor(kss, 4);
    kss += __shfl_xor(kss, 8); kss += __shfl_xor(kss, 16);
    float kscale = rsqrtf(kss * (1.f / 64.f) + 1e-6f);
    kbuf[kidx] = kraw0; kbuf[kidx + 1] = kraw1;

    {
        float va = rkvrow[2560 + kidx] + V_bias[kidx];
        float vb2 = rkvrow[2560 + kidx + 1] + V_bias[kidx + 1];
        float gv0 = sigmf(smrow[4096 + kidx] + v0b[kidx]);
        float gv1 = sigmf(smrow[4096 + kidx + 1] + v0b[kidx + 1]);
        vbuf[kidx] = va + (v_first[(size_t)bt * 512 + kidx] - va) * gv0;
        vbuf[kidx + 1] = vb2 + (v_first[(size_t)bt * 512 + kidx + 1] - vb2) * gv1;
    }
    __syncthreads();

    float rf[8];
    #pragma unroll
    for (int j = 0; j < 8; ++j) {
        int nn = off + j;
        int nn2 = (nn + 32) & 63;
        float val = rbuf[h * 64 + nn] * rscale * ln_r[nn];
        float oth = rbuf[h * 64 + nn2] * rscale * ln_r[nn2];
        float rot = (nn < 32) ? -oth : oth;
        rf[j] = val * cosb[nn] + rot * sinb[nn];
    }
    float kfv[2];
    #pragma unroll
    for (int j = 0; j < 2; ++j) {
        int nn = ko2 + j;
        int nn2 = (nn + 32) & 63;
        float val = kbuf[kvh * 64 + nn] * kscale * ln_k[nn];
        float oth = kbuf[kvh * 64 + nn2] * kscale * ln_k[nn2];
        float rot = (nn < 32) ? -oth : oth;
        float kr = val * cosb[nn] + rot * sinb[nn];
        float gk = sigmf(smrow[6656 + kvh * 64 + nn] + k0b[kvh * 64 + nn]);
        kfv[j] = kr + (k_first[(size_t)bt * 512 + kvh * 64 + nn] - kr) * gk;
    }
    __syncthreads();
    kbuf[kidx] = kfv[0]; kbuf[kidx + 1] = kfv[1];
    float kn = kfv[0] * kfv[0] + kfv[1] * kfv[1];
    kn += __shfl_xor(kn, 1); kn += __shfl_xor(kn, 2); kn += __shfl_xor(kn, 4);
    kn += __shfl_xor(kn, 8); kn += __shfl_xor(kn, 16);
    if ((tid & 31) == 0) knorms[kvh] = fmaxf(sqrtf(kn), 1e-12f);
    __syncthreads();

    const float knv = knorms[h >> 2];
    char* scb = SC + ((size_t)(b * H_ + h) * T_ + t) * 896;
    __hip_bfloat16* us = (__hip_bfloat16*)scb;
    float* df = (float*)(scb + 640);
    float4 w1a = *(const float4*)(smrow + n0);
    float4 w1b = *(const float4*)(smrow + n0 + 4);
    float4 ara = *(const float4*)(smrow + 2048 + n0);
    float4 arb = *(const float4*)(smrow + 2048 + n0 + 4);
    float w1arr[8] = {w1a.x, w1a.y, w1a.z, w1a.w, w1b.x, w1b.y, w1b.z, w1b.w};
    float aarr[8] = {ara.x, ara.y, ara.z, ara.w, arb.x, arb.y, arb.z, arb.w};
    float bsum = 0.f;
    #pragma unroll
    for (int j = 0; j < 8; ++j) {
        int nn = off + j, n = n0 + j;
        float w1 = w1arr[j] + w0[n];
        float w2v = -log1pf(expf(-w1)) - 0.5f;
        float av = sigmf(aarr[j] + a0[n]);
        float dec = expf(-expf(w2v));
        float kb = kbuf[(h >> 2) * 64 + nn];
        float vbv = vbuf[(h >> 2) * 64 + nn];
        float kkv = kb / knv;
        float ksc = kb * (1.f - w2v + av);
        us[nn]       = __float2bfloat16(rf[j]);
        us[64 + nn]  = __float2bfloat16(ksc);
        us[128 + nn] = __float2bfloat16(-kkv);
        us[192 + nn] = __float2bfloat16(kkv * av);
        us[256 + nn] = __float2bfloat16(vbv);
        df[nn] = dec;
        VB[(size_t)bt * HN_ + n] = __float2bfloat16(vbv);
        bsum += rf[j] * ksc * r_k[h * 64 + nn];
    }
    bsum += __shfl_xor(bsum, 1); bsum += __shfl_xor(bsum, 2); bsum += __shfl_xor(bsum, 4);
    if ((tid & 7) == 0) SB[bt * H_ + h] = bsum;
}

// ---------------- chunked scan pass 1: per-chunk P, S_loc, q_t, oloc_t(->O) ----------------
__global__ __launch_bounds__(64, 2) void scan_pass1(
    const char* __restrict__ SC, float* __restrict__ Q, float* __restrict__ O,
    float* __restrict__ Pf, float* __restrict__ Sf) {
    const int chunk = blockIdx.x;
    const int bh = chunk >> 4, c = chunk & 15;
    const int b = bh >> 5, h = bh & 31;
    const int lane = threadIdx.x;
    const char* base = SC + ((size_t)bh * T_ + (size_t)c * CH) * 896;

    f32x4 P4[16], S4[16];
    #pragma unroll
    for (int j = 0; j < 16; ++j) {
        #pragma unroll
        for (int e = 0; e < 4; ++e) {
            P4[j][e] = (4 * j + e == lane) ? 1.f : 0.f;
            S4[j][e] = 0.f;
        }
    }
    __shared__ __align__(16) float ld[2][5][64];
    float pr_r, pr_k, pr_a, pr_b, pr_v, pr_d;
    auto LOADT = [&](int t) {
        const __hip_bfloat16* us = (const __hip_bfloat16*)(base + (size_t)t * 896);
        pr_r = __bfloat162float(us[lane]);
        pr_k = __bfloat162float(us[64 + lane]);
        pr_a = __bfloat162float(us[128 + lane]);
        pr_b = __bfloat162float(us[192 + lane]);
        pr_v = __bfloat162float(us[256 + lane]);
        pr_d = *(const float*)(base + (size_t)t * 896 + 640 + 4 * lane);
    };
    LOADT(0);
    float* qbase = Q + (size_t)chunk * CH * 64 + lane;
    float* obase = O + ((size_t)b * T_ + (size_t)c * CH) * HN_ + h * 64 + lane;
    for (int t = 0; t < CH; ++t) {
        const int buf = t & 1;
        const float vt = pr_v;
        ld[buf][0][lane] = pr_a;
        ld[buf][1][lane] = pr_b;
        ld[buf][2][lane] = pr_d;
        ld[buf][3][lane] = pr_k;
        ld[buf][4][lane] = pr_r;
        __syncthreads();
        if (t + 1 < CH) LOADT(t + 1);
        f32x4 cp4 = {0,0,0,0}, sa4 = {0,0,0,0};
        #pragma unroll
        for (int j = 0; j < 16; ++j) {
            f32x4 a4 = *(const f32x4*)&ld[buf][0][4 * j];
            cp4 += P4[j] * a4;
            sa4 += S4[j] * a4;
        }
        const float cP = cp4[0] + cp4[1] + cp4[2] + cp4[3];
        const float sa = sa4[0] + sa4[1] + sa4[2] + sa4[3];
        const f32x4 cPv = {cP, cP, cP, cP}, sav = {sa, sa, sa, sa}, vtv = {vt, vt, vt, vt};
        f32x4 q4 = {0,0,0,0}, ol4 = {0,0,0,0};
        #pragma unroll
        for (int j = 0; j < 16; ++j) {
            f32x4 d4 = *(const f32x4*)&ld[buf][2][4 * j];
            f32x4 b4 = *(const f32x4*)&ld[buf][1][4 * j];
            f32x4 k4 = *(const f32x4*)&ld[buf][3][4 * j];
            f32x4 r4 = *(const f32x4*)&ld[buf][4][4 * j];
            f32x4 Pn = P4[j] * d4 + cPv * b4;
            f32x4 Sn = S4[j] * d4 + sav * b4 + vtv * k4;
            P4[j] = Pn; S4[j] = Sn;
            q4 += Pn * r4;
            ol4 += Sn * r4;
        }
        qbase[(size_t)t * 64] = q4[0] + q4[1] + q4[2] + q4[3];
        obase[(size_t)t * HN_] = ol4[0] + ol4[1] + ol4[2] + ol4[3];  // oloc, unscaled
        __syncthreads();
    }
    float* pf = Pf + (size_t)chunk * 4096 + lane * 64;
    float* sf = Sf + (size_t)chunk * 4096 + lane * 64;
    #pragma unroll
    for (int j = 0; j < 16; ++j) {
        *(f32x4*)(pf + 4 * j) = P4[j];
        *(f32x4*)(sf + 4 * j) = S4[j];
    }
}

// ---------------- pass 2: propagate chunk-initial states (Sf -> Sinit in place) ----------------
// 4 blocks per bh (row-split: 16 S-rows each); thread owns one f32x4 of S.
__global__ __launch_bounds__(256) void scan_pass2(
    const float* __restrict__ Pf, float* __restrict__ Sf, const float* __restrict__ state) {
    const int blk = blockIdx.x;
    const int bh = blk >> 2, rb = blk & 3;
    const int tid = threadIdx.x;
    const int lv = tid >> 4, c0 = (tid & 15) << 2;
    __shared__ __align__(16) float S[16][68];
    __shared__ __align__(16) float P[64][64];

    // initial state rows [16rb, 16rb+16)
    *(f32x4*)&S[lv][c0] = *(const f32x4*)&state[(size_t)bh * 4096 + 1024 * rb + tid * 4];
    // stage chunk 0's P
    const size_t pbase = (size_t)(bh * NCH) * 4096;
    {
        f32x4 p0[4];
        #pragma unroll
        for (int j = 0; j < 4; ++j) p0[j] = *(const f32x4*)&Pf[pbase + tid * 16 + 4 * j];
        #pragma unroll
        for (int j = 0; j < 4; ++j) *(f32x4*)(&P[0][0] + tid * 16 + 4 * j) = p0[j];
    }
    __syncthreads();

    for (int c = 0; c < NCH; ++c) {
        const size_t ck = (size_t)(bh * NCH + c) * 4096;
        // prefetch next chunk's P into regs (hidden under compute)
        f32x4 pp[4];
        if (c + 1 < NCH) {
            #pragma unroll
            for (int j = 0; j < 4; ++j) pp[j] = *(const f32x4*)&Pf[ck + 4096 + tid * 16 + 4 * j];
        }
        f32x4 acc = *(const f32x4*)&Sf[ck + 1024 * rb + tid * 4];   // S_loc(c)
        f32x4 cur = *(const f32x4*)&S[lv][c0];                      // Sinit(c) = state before chunk c
        // acc += S[lv][:] · P[:, c0..c0+3]
        #pragma unroll 4
        for (int k4 = 0; k4 < 64; k4 += 4) {
            f32x4 sk4 = *(const f32x4*)&S[lv][k4];
            #pragma unroll
            for (int kk = 0; kk < 4; ++kk) {
                f32x4 pr = *(const f32x4*)&P[k4 + kk][c0];
                f32x4 sv = {sk4[kk], sk4[kk], sk4[kk], sk4[kk]};
                acc += sv * pr;
            }
        }
        __syncthreads();                       // all reads of S and P done
        *(f32x4*)&S[lv][c0] = acc;             // S := S·P + S_loc
        if (c + 1 < NCH) {
            #pragma unroll
            for (int j = 0; j < 4; ++j) *(f32x4*)(&P[0][0] + tid * 16 + 4 * j) = pp[j];
        }
        *(f32x4*)&Sf[ck + 1024 * rb + tid * 4] = cur;  // store Sinit(c)
        __syncthreads();
    }
}

// ---------------- pass 3: O[t] = (Sinit · q_t + oloc_t) * N^-0.5, in place ----------------
__global__ __launch_bounds__(64) void scan_pass3(
    const float* __restrict__ Q, const float* __restrict__ Sinit, float* __restrict__ O) {
    const int chunk = blockIdx.x;
    const int bh = chunk >> 4, c = chunk & 15;
    const int b = bh >> 5, h = bh & 31;
    const int t = threadIdx.x;
    __shared__ __align__(16) float S[64][64];
    #pragma unroll
    for (int j = 0; j < 16; ++j)
        *(f32x4*)&S[t][4 * j] = *(const f32x4*)&Sinit[(size_t)chunk * 4096 + (size_t)t * 64 + 4 * j];
    __syncthreads();
    float q[64];
    #pragma unroll
    for (int j = 0; j < 16; ++j)
        *(f32x4*)&q[4 * j] = *(const f32x4*)&Q[((size_t)chunk * CH + t) * 64 + 4 * j];
    float* orow = O + ((size_t)b * T_ + (size_t)c * CH + t) * HN_ + h * 64;
    #pragma unroll 4
    for (int v = 0; v < 64; ++v) {
        f32x4 a = {0, 0, 0, 0};
        #pragma unroll
        for (int j = 0; j < 16; ++j)
            a += *(const f32x4*)&S[v][4 * j] * *(const f32x4*)&q[4 * j];
        orow[v] = (a[0] + a[1] + a[2] + a[3] + orow[v]) * 0.125f;
    }
}

// ---------------- post: U = (o + bonus_scalar*v) * g -> bf16 ----------------
__global__ void post_kernel(const float* __restrict__ O, const float* __restrict__ SB,
                            const __hip_bfloat16* __restrict__ VB, const float* __restrict__ SM,
                            __hip_bfloat16* __restrict__ Ub) {
    long i = (long)blockIdx.x * 256 + threadIdx.x;
    if (i >= (long)MTOK * HN_) return;
    int bt = (int)(i >> 11), n = (int)(i & 2047), h = n >> 6;
    float u = (O[i] + SB[bt * H_ + h] * __bfloat162float(VB[i])) * SM[(size_t)bt * SMN + 4608 + n];
    Ub[i] = __float2bfloat16(u);
}

extern "C" void kernel_launch(void* const* d_in, const int* in_sizes, int n_in,
                              void* d_out, int out_size, void* d_ws, size_t ws_size,
                              hipStream_t stream) {
    (void)in_sizes; (void)n_in; (void)out_size; (void)ws_size;
    const float* x_in    = (const float*)d_in[0];
    const float* v_first = (const float*)d_in[1];
    const float* k_first = (const float*)d_in[2];
    const float* state   = (const float*)d_in[3];
    const float* calc_cos= (const float*)d_in[4];
    const float* calc_sin= (const float*)d_in[5];
    const float* wavgk1  = (const float*)d_in[6];
    const float* w0      = (const float*)d_in[7];
    const float* w2      = (const float*)d_in[8];
    const float* a0      = (const float*)d_in[9];
    const float* a2      = (const float*)d_in[10];
    const float* v0      = (const float*)d_in[11];
    const float* v2      = (const float*)d_in[12];
    const float* g2      = (const float*)d_in[13];
    const float* k0      = (const float*)d_in[14];
    const float* k2      = (const float*)d_in[15];
    const float* r_k     = (const float*)d_in[16];
    const float* RKV_w   = (const float*)d_in[17];
    const float* O_w     = (const float*)d_in[18];
    const float* R_bias  = (const float*)d_in[19];
    const float* K_bias  = (const float*)d_in[20];
    const float* V_bias  = (const float*)d_in[21];
    const float* O_bias  = (const float*)d_in[22];
    const float* ln_r    = (const float*)d_in[23];
    const float* ln_k    = (const float*)d_in[24];
    const float* ln1     = (const float*)d_in[25];
    float* out = (float*)d_out;

    char* ws = (char*)d_ws;
    size_t off = 0;
    auto alloc = [&](size_t bytes) -> char* {
        char* p = ws + off;
        off = (off + bytes + 255) & ~(size_t)255;
        return p;
    };
    // ---- persistent region ----
    float* SMf = (float*)alloc((size_t)MTOK * SMN * 4);               // gemm3 -> post
    char*  SCb = alloc((size_t)64 * T_ * 896);                        // compose -> pass1
    __hip_bfloat16* Ub = (__hip_bfloat16*)SCb;                        // aliases SCb (post -> final gemm)
    __hip_bfloat16* VBb = (__hip_bfloat16*)alloc((size_t)MTOK * HN_ * 2); // compose -> post
    float* SBf = (float*)alloc((size_t)MTOK * H_ * 4);                // compose -> post
    float* Of  = (float*)alloc((size_t)MTOK * HN_ * 4);               // pass1 -> post
    __hip_bfloat16* OWb = (__hip_bfloat16*)alloc((size_t)2048 * 2048 * 2); // prep -> final gemm

    // ---- overlapped region: stage A (pre-scan) ----
    size_t ovl = off;
    __hip_bfloat16* Xb     = (__hip_bfloat16*)alloc((size_t)MTOK * HN_ * 2);
    __hip_bfloat16* RKVb   = (__hip_bfloat16*)alloc((size_t)3072 * 2048 * 2);
    __hip_bfloat16* WT1b   = (__hip_bfloat16*)alloc((size_t)320 * 2048 * 2);
    __hip_bfloat16* Wcatb  = (__hip_bfloat16*)alloc((size_t)SMN * KCAT * 2);
    __hip_bfloat16* XWmodb = (__hip_bfloat16*)alloc((size_t)MTOK * KCAT * 2);
    float* RKVf  = (float*)alloc((size_t)MTOK * 3072 * 4);
    float* XWraw = (float*)alloc((size_t)MTOK * KCAT * 4);
    // ---- overlapped region: stage B (scan) — reuses stage A space ----
    off = ovl;
    float* Qf  = (float*)alloc((size_t)NCHUNK * CH * 64 * 4);         // pass1 -> pass3
    float* Pff = (float*)alloc((size_t)NCHUNK * 4096 * 4);            // pass1 -> pass2
    float* Sff = (float*)alloc((size_t)NCHUNK * 4096 * 4);            // pass1 -> pass3

    // weight prep
    f2b_kernel<<<(3072 * 2048 + 255) / 256, 256, 0, stream>>>(RKV_w, RKVb, 3072 * 2048);
    f2b_kernel<<<(2048 * 2048 + 255) / 256, 256, 0, stream>>>(O_w, OWb, 2048 * 2048);
    transpose_f2b_kernel<<<(320 * 2048 + 255) / 256, 256, 0, stream>>>(wavgk1, WT1b, 2048, 320);
    build_wcat_kernel<<<(SMN * KCAT + 255) / 256, 256, 0, stream>>>(w2, a2, v2, g2, k2, Wcatb);

    // x = rmsnorm(x_in, ln1) -> bf16
    rmsnorm_kernel<<<MTOK, 256, 0, stream>>>(x_in, ln1, Xb);

    // big GEMMs
    gemm_bt<<<dim3(3072 / 64, MTOK / 64), 256, 0, stream>>>(Xb, RKVb, RKVf, MTOK, 3072, 2048, nullptr, nullptr);
    gemm_bt<<<dim3(320 / 64, MTOK / 64), 256, 0, stream>>>(Xb, WT1b, XWraw, MTOK, 320, 2048, nullptr, nullptr);
    xwmod_kernel<<<(MTOK * KCAT + 255) / 256, 256, 0, stream>>>(XWraw, XWmodb);
    gemm_bt<<<dim3(SMN / 64, MTOK / 64), 256, 0, stream>>>(XWmodb, Wcatb, SMf, MTOK, SMN, KCAT, nullptr, nullptr);

    // compose scan records
    compose_kernel<<<MTOK, 256, 0, stream>>>(RKVf, SMf, v_first, k_first, calc_cos, calc_sin,
                                             R_bias, K_bias, V_bias, w0, a0, v0, k0,
                                             ln_r, ln_k, r_k, SCb, VBb, SBf);

    // chunked RWKV scan: pass1 (parallel) -> pass2 (chunk-sequential, row-split) -> pass3 (parallel)
    scan_pass1<<<NCHUNK, 64, 0, stream>>>(SCb, Qf, Of, Pff, Sff);
    scan_pass2<<<B_ * H_ * 4, 256, 0, stream>>>(Pff, Sff, state);
    scan_pass3<<<NCHUNK, 64, 0, stream>>>(Qf, Sff, Of);

    // post + output GEMM (adds x_in and O_bias in epilogue)
    post_kernel<<<(MTOK * HN_ + 255) / 256, 256, 0, stream>>>(Of, SBf, VBb, SMf, Ub);
    gemm_bt<<<dim3(HN_ / 64, MTOK / 64), 256, 0, stream>>>(Ub, OWb, out, MTOK, HN_, 2048, O_bias, x_in);
}